// Round 1
// 365.118 us; speedup vs baseline: 1.0741x; 1.0741x over previous
//
#include <hip/hip_runtime.h>
#include <math.h>

// Problem constants (B=8, V=256, H=128)
#define BV 2048            // B*V rows
#define V_ 256
#define H_ 128

__device__ __forceinline__ float silu_f(float x) {
    return x / (1.0f + expf(-x));
}

// ---------------------------------------------------------------------------
// k1: h0 = silu(h @ W_pre + b_pre), skip = silu(h @ W_skip + b_skip)
// 8 rows per block, 512 threads (16 waves/CU across 256 blocks -> better
// latency hiding for the L2-bound W-row stream than the old 256-thread/
// 1-block-per-CU version). h tile staged in LDS via float4; W columns
// streamed coalesced from L2. Per-output accumulation order unchanged
// (k ascending) -> bit-identical to previous version.
// ---------------------------------------------------------------------------
__global__ __launch_bounds__(512) void k1_pre_skip(
    const float* __restrict__ h,
    const float* __restrict__ W_pre, const float* __restrict__ b_pre,
    const float* __restrict__ W_skip, const float* __restrict__ b_skip,
    float* __restrict__ h0ws, float* __restrict__ skipws)
{
    const int t = threadIdx.x;
    const int rbase = blockIdx.x * 8;
    __shared__ float s_h[8 * H_];
    if (t < 256) {
        reinterpret_cast<float4*>(s_h)[t] =
            reinterpret_cast<const float4*>(h + (size_t)rbase * H_)[t];
    }
    __syncthreads();

    const int c  = t & 127;
    const int r0 = (t >> 7) * 2;                // 0,2,4,6
    float a0[2] = {0.f, 0.f};
    float a1[2] = {0.f, 0.f};
    #pragma unroll 8
    for (int k = 0; k < H_; ++k) {
        float w0 = W_pre[k * H_ + c];
        float w1 = W_skip[k * H_ + c];
        #pragma unroll
        for (int r = 0; r < 2; ++r) {
            float hv = s_h[(r0 + r) * H_ + k];
            a0[r] += hv * w0;
            a1[r] += hv * w1;
        }
    }
    const float bp = b_pre[c], bs = b_skip[c];
    #pragma unroll
    for (int r = 0; r < 2; ++r) {
        int row = rbase + r0 + r;
        h0ws[row * H_ + c]   = silu_f(a0[r] + bp);
        skipws[row * H_ + c] = silu_f(a1[r] + bs);
    }
}

// ---------------------------------------------------------------------------
// k2: fused edge-max + post GEMM + skip.
//   neigh[h] = max_j ( graph[b,i,j]!=0 ? 0 : e[b,i,j,h]*h0[b,j,h] )
//   h1 = silu([h0_i, neigh] @ W_post + b_post);  out = silu(skip_i + h1)
// One block per (b,i). Compact unmasked j's (ballot+popcount), transpose the
// list so group jg's next 4 indices are one broadcast int4 LDS read.
// Thread t: h4 = t%32 (float4 lane), jg = t/32 (8 j-groups). Each chunk
// issues 8 float4 e-loads + 8 float4 h0-loads before any vmcnt wait.
// Skips ~50% of the 268 MB e stream. The per-row W_post GEMM epilogue
// (128 KB from per-XCD-hot L2) replaces the old standalone k3 dispatch and
// the nws HBM round-trip; it hides under other blocks' HBM streaming.
// ---------------------------------------------------------------------------
__global__ __launch_bounds__(256, 4) void k2_edge_max_post(
    const float4* __restrict__ e4,
    const int* __restrict__ graph,
    const float4* __restrict__ h04,
    const float* __restrict__ h0ws,
    const float* __restrict__ skipws,
    const float* __restrict__ W_post, const float* __restrict__ b_post,
    float* __restrict__ out)
{
    const int t  = threadIdx.x;
    const int bi = blockIdx.x;          // b*256 + i
    const int b  = bi >> 8;

    __shared__ int   s_list[V_];
    __shared__ int   s_listT[V_];       // [jg][it] transposed, int4-readable
    __shared__ int   s_wcnt[4];
    __shared__ float s_red[8 * H_];
    __shared__ float s_x[2 * H_];       // [h0 row | neigh]
    __shared__ float s_part[2 * H_];

    // --- compact unmasked j's ---
    const int  g    = graph[bi * V_ + t];
    const bool keep = (g == 0);
    unsigned long long bal = __ballot(keep);
    const int lane = t & 63;
    const int wv   = t >> 6;
    if (lane == 0) s_wcnt[wv] = __popcll(bal);
    __syncthreads();
    const int count = s_wcnt[0] + s_wcnt[1] + s_wcnt[2] + s_wcnt[3];
    int off = 0;
    for (int w = 0; w < wv; ++w) off += s_wcnt[w];
    if (keep) s_list[off + __popcll(bal & ((1ull << lane) - 1ull))] = t;
    __syncthreads();

    // --- transpose + pad to multiple of 32 (duplicates are max-idempotent) ---
    const int j0  = (count > 0) ? s_list[0] : 0;
    {
        const int jgT = t >> 5;          // 0..7
        const int itT = t & 31;          // 0..31
        const int idx = itT * 8 + jgT;   // position in compacted order
        s_listT[jgT * 32 + itT] = (idx < count) ? s_list[idx] : j0;
    }
    if (t < H_) s_x[t] = h0ws[bi * H_ + t];   // stage h0 row i for epilogue
    __syncthreads();

    // --- stream unmasked e rows ---
    const int h4 = t & 31;
    const int jg = t >> 5;
    const float4* __restrict__ ep = e4 + (size_t)bi * (V_ * 32) + h4;
    const float4* __restrict__ hp = h04 + ((size_t)(b << 8) * 32) + h4;
    const int4*   __restrict__ lt = reinterpret_cast<const int4*>(s_listT) + jg * 8;

    const int chunks = (count + 31) >> 5;   // each chunk = 4 j's per group
    float4 vmax = make_float4(-INFINITY, -INFINITY, -INFINITY, -INFINITY);
    #pragma unroll 2
    for (int c0 = 0; c0 < chunks; ++c0) {
        int4 j4 = lt[c0];
        float4 ea = ep[j4.x * 32];
        float4 eb = ep[j4.y * 32];
        float4 ec = ep[j4.z * 32];
        float4 ed = ep[j4.w * 32];
        float4 ha = hp[j4.x * 32];
        float4 hb = hp[j4.y * 32];
        float4 hc = hp[j4.z * 32];
        float4 hd = hp[j4.w * 32];
        vmax.x = fmaxf(vmax.x, ea.x * ha.x); vmax.y = fmaxf(vmax.y, ea.y * ha.y);
        vmax.z = fmaxf(vmax.z, ea.z * ha.z); vmax.w = fmaxf(vmax.w, ea.w * ha.w);
        vmax.x = fmaxf(vmax.x, eb.x * hb.x); vmax.y = fmaxf(vmax.y, eb.y * hb.y);
        vmax.z = fmaxf(vmax.z, eb.z * hb.z); vmax.w = fmaxf(vmax.w, eb.w * hb.w);
        vmax.x = fmaxf(vmax.x, ec.x * hc.x); vmax.y = fmaxf(vmax.y, ec.y * hc.y);
        vmax.z = fmaxf(vmax.z, ec.z * hc.z); vmax.w = fmaxf(vmax.w, ec.w * hc.w);
        vmax.x = fmaxf(vmax.x, ed.x * hd.x); vmax.y = fmaxf(vmax.y, ed.y * hd.y);
        vmax.z = fmaxf(vmax.z, ed.z * hd.z); vmax.w = fmaxf(vmax.w, ed.w * hd.w);
    }

    // --- reduce the 8 j-groups -> neigh into s_x[H_..2H_) ---
    *reinterpret_cast<float4*>(&s_red[jg * H_ + h4 * 4]) = vmax;
    __syncthreads();
    if (t < H_) {
        float m = s_red[t];
        #pragma unroll
        for (int gg = 1; gg < 8; ++gg) m = fmaxf(m, s_red[gg * H_ + t]);
        if (count < V_) m = fmaxf(m, 0.0f);   // masked entries contribute 0
        s_x[H_ + t] = m;                       // count==0 -> max(-inf,0)=0
    }
    __syncthreads();

    // --- epilogue: h1 = silu(x @ W_post + b_post); out = silu(skip + h1) ---
    // thread (c, half): half covers k in [half*128, half*128+128)
    const int c    = t & 127;
    const int half = t >> 7;
    const float* __restrict__ wp = W_post + (size_t)(half * H_) * H_ + c;
    float acc = 0.f;
    #pragma unroll 8
    for (int kk = 0; kk < H_; ++kk) {
        acc += s_x[half * H_ + kk] * wp[(size_t)kk * H_];
    }
    s_part[half * H_ + c] = acc;
    __syncthreads();
    if (t < H_) {
        float h1 = silu_f(s_part[t] + s_part[H_ + t] + b_post[t]);
        out[bi * H_ + t] = silu_f(skipws[bi * H_ + t] + h1);
    }
}

// ---------------------------------------------------------------------------
extern "C" void kernel_launch(void* const* d_in, const int* in_sizes, int n_in,
                              void* d_out, int out_size, void* d_ws, size_t ws_size,
                              hipStream_t stream)
{
    const float* h      = (const float*)d_in[0];
    const float* e      = (const float*)d_in[1];
    const int*   graph  = (const int*)  d_in[2];
    const float* W_pre  = (const float*)d_in[3];
    const float* b_pre  = (const float*)d_in[4];
    const float* W_post = (const float*)d_in[5];
    const float* b_post = (const float*)d_in[6];
    const float* W_skip = (const float*)d_in[7];
    const float* b_skip = (const float*)d_in[8];
    float* out = (float*)d_out;

    float* ws     = (float*)d_ws;
    float* h0ws   = ws;                    // BV*H floats = 1 MB
    float* skipws = ws + BV * H_;          // 1 MB

    k1_pre_skip<<<BV / 8, 512, 0, stream>>>(h, W_pre, b_pre, W_skip, b_skip,
                                            h0ws, skipws);
    k2_edge_max_post<<<BV, 256, 0, stream>>>((const float4*)e, graph,
                                             (const float4*)h0ws,
                                             h0ws, skipws,
                                             W_post, b_post, out);
}

// Round 2
// 361.521 us; speedup vs baseline: 1.0848x; 1.0099x over previous
//
#include <hip/hip_runtime.h>
#include <math.h>

// Problem constants (B=8, V=256, H=128)
#define BV 2048            // B*V rows
#define V_ 256
#define H_ 128

__device__ __forceinline__ float silu_f(float x) {
    return x / (1.0f + expf(-x));
}

// ---------------------------------------------------------------------------
// k1: h0 = silu(h @ W_pre + b_pre), skip = silu(h @ W_skip + b_skip)
// 8 rows per block, 512 threads. h tile staged in LDS via float4; W columns
// streamed coalesced from L2. Accumulation order (k ascending) bit-identical
// to previous rounds.
// ---------------------------------------------------------------------------
__global__ __launch_bounds__(512) void k1_pre_skip(
    const float* __restrict__ h,
    const float* __restrict__ W_pre, const float* __restrict__ b_pre,
    const float* __restrict__ W_skip, const float* __restrict__ b_skip,
    float* __restrict__ h0ws, float* __restrict__ skipws)
{
    const int t = threadIdx.x;
    const int rbase = blockIdx.x * 8;
    __shared__ float s_h[8 * H_];
    if (t < 256) {
        reinterpret_cast<float4*>(s_h)[t] =
            reinterpret_cast<const float4*>(h + (size_t)rbase * H_)[t];
    }
    __syncthreads();

    const int c  = t & 127;
    const int r0 = (t >> 7) * 2;                // 0,2,4,6
    float a0[2] = {0.f, 0.f};
    float a1[2] = {0.f, 0.f};
    #pragma unroll 8
    for (int k = 0; k < H_; ++k) {
        float w0 = W_pre[k * H_ + c];
        float w1 = W_skip[k * H_ + c];
        #pragma unroll
        for (int r = 0; r < 2; ++r) {
            float hv = s_h[(r0 + r) * H_ + k];
            a0[r] += hv * w0;
            a1[r] += hv * w1;
        }
    }
    const float bp = b_pre[c], bs = b_skip[c];
    #pragma unroll
    for (int r = 0; r < 2; ++r) {
        int row = rbase + r0 + r;
        h0ws[row * H_ + c]   = silu_f(a0[r] + bp);
        skipws[row * H_ + c] = silu_f(a1[r] + bs);
    }
}

// ---------------------------------------------------------------------------
// k2: fused edge-max + post GEMM + skip, TWO rows (b,i), (b,i+1) per block.
//   neigh[h] = max_j ( graph[b,i,j]!=0 ? 0 : e[b,i,j,h]*h0[b,j,h] )
//   h1 = silu([h0_i, neigh] @ W_post + b_post);  out = silu(skip_i + h1)
// 1024 blocks x 256 threads = exactly 4 blocks/CU, all resident, one round.
// Halves the preamble count and halves per-block W_post L2 re-reads
// (268 MB -> 134 MB) vs the 1-row version.
// Compaction: wave w -> (row w>>1, half w&1), two 64-lane ballots each.
// Streaming: thread t: h4 = t%32 (float4 lane), grp = t/32 in [0,8);
// row = grp>>2, group-in-row gs = grp&3. Each chunk issues 8 float4 e-loads
// + 8 float4 h0-loads before any vmcnt wait (x2 with unroll 2).
// ---------------------------------------------------------------------------
__global__ __launch_bounds__(256, 4) void k2_edge_max_post(
    const float4* __restrict__ e4,
    const int* __restrict__ graph,
    const float4* __restrict__ h04,
    const float* __restrict__ h0ws,
    const float* __restrict__ skipws,
    const float* __restrict__ W_post, const float* __restrict__ b_post,
    float* __restrict__ out)
{
    const int t   = threadIdx.x;
    const int bi0 = blockIdx.x * 2;      // first row index (b*256 + i)
    const int b   = bi0 >> 8;

    __shared__ int   s_list[2][V_];
    __shared__ int   s_listT[2][V_];     // per-row transposed, int4-readable
    __shared__ int   s_cnt[2][4];
    __shared__ float s_red[8 * H_];
    __shared__ float s_x[2][2 * H_];     // per row: [h0 | neigh]
    __shared__ float s_part[4 * H_];     // [half][row][c]

    // --- parallel compaction: wave w -> (row rw = w>>1, half hf = w&1) ---
    const int lane = t & 63;
    const int wv   = t >> 6;
    const int rw   = wv >> 1;
    const int hf   = wv & 1;
    const int jA   = hf * 128 + lane;    // this wave's first j segment
    const int gA = graph[(bi0 + rw) * V_ + jA];
    const int gB = graph[(bi0 + rw) * V_ + jA + 64];
    const bool keepA = (gA == 0), keepB = (gB == 0);
    unsigned long long balA = __ballot(keepA);
    unsigned long long balB = __ballot(keepB);
    if (lane == 0) { s_cnt[rw][hf * 2]     = __popcll(balA);
                     s_cnt[rw][hf * 2 + 1] = __popcll(balB); }
    // stage h0 rows for the epilogue while counts land
    {
        const int r = t >> 7, hh = t & 127;
        s_x[r][hh] = h0ws[(bi0 + r) * H_ + hh];
    }
    __syncthreads();

    // --- scatter compacted j's (offsets from per-segment counts) ---
    {
        const int c0 = s_cnt[rw][0], c1 = s_cnt[rw][1], c2 = s_cnt[rw][2];
        const int pre[4] = {0, c0, c0 + c1, c0 + c1 + c2};
        const unsigned long long below = (1ull << lane) - 1ull;
        if (keepA) s_list[rw][pre[hf * 2]     + __popcll(balA & below)] = jA;
        if (keepB) s_list[rw][pre[hf * 2 + 1] + __popcll(balB & below)] = jA + 64;
    }
    __syncthreads();

    // --- transpose + pad (duplicates are max-idempotent) ---
    {
        const int r   = t >> 7;
        const int q   = t & 127;
        const int gsT = q >> 5;          // 0..3
        const int it0 = q & 31;
        const int cnt = s_cnt[r][0] + s_cnt[r][1] + s_cnt[r][2] + s_cnt[r][3];
        const int j0  = (cnt > 0) ? s_list[r][0] : 0;
        #pragma unroll
        for (int rep = 0; rep < 2; ++rep) {
            const int itT = it0 + rep * 32;          // 0..63
            const int idx = itT * 4 + gsT;           // position in compacted order
            s_listT[r][gsT * 64 + itT] = (idx < cnt) ? s_list[r][idx] : j0;
        }
    }
    __syncthreads();

    // --- stream unmasked e rows ---
    const int h4  = t & 31;
    const int grp = t >> 5;              // 0..7
    const int gr  = grp >> 2;            // row within block
    const int gs  = grp & 3;             // group within row
    const int bi  = bi0 + gr;
    const float4* __restrict__ ep = e4 + (size_t)bi * (V_ * 32) + h4;
    const float4* __restrict__ hp = h04 + ((size_t)(b << 8) * 32) + h4;
    const int4*   __restrict__ lt =
        reinterpret_cast<const int4*>(&s_listT[gr][0]) + gs * 16;
    const int cnt_g  = s_cnt[gr][0] + s_cnt[gr][1] + s_cnt[gr][2] + s_cnt[gr][3];
    const int chunks = (cnt_g + 15) >> 4;   // 16 j's per row per chunk

    float4 vmax = make_float4(-INFINITY, -INFINITY, -INFINITY, -INFINITY);
    #pragma unroll 2
    for (int c0 = 0; c0 < chunks; ++c0) {
        int4 j4 = lt[c0];
        float4 ea = ep[j4.x * 32];
        float4 eb = ep[j4.y * 32];
        float4 ec = ep[j4.z * 32];
        float4 ed = ep[j4.w * 32];
        float4 ha = hp[j4.x * 32];
        float4 hb = hp[j4.y * 32];
        float4 hc = hp[j4.z * 32];
        float4 hd = hp[j4.w * 32];
        vmax.x = fmaxf(vmax.x, ea.x * ha.x); vmax.y = fmaxf(vmax.y, ea.y * ha.y);
        vmax.z = fmaxf(vmax.z, ea.z * ha.z); vmax.w = fmaxf(vmax.w, ea.w * ha.w);
        vmax.x = fmaxf(vmax.x, eb.x * hb.x); vmax.y = fmaxf(vmax.y, eb.y * hb.y);
        vmax.z = fmaxf(vmax.z, eb.z * hb.z); vmax.w = fmaxf(vmax.w, eb.w * hb.w);
        vmax.x = fmaxf(vmax.x, ec.x * hc.x); vmax.y = fmaxf(vmax.y, ec.y * hc.y);
        vmax.z = fmaxf(vmax.z, ec.z * hc.z); vmax.w = fmaxf(vmax.w, ec.w * hc.w);
        vmax.x = fmaxf(vmax.x, ed.x * hd.x); vmax.y = fmaxf(vmax.y, ed.y * hd.y);
        vmax.z = fmaxf(vmax.z, ed.z * hd.z); vmax.w = fmaxf(vmax.w, ed.w * hd.w);
    }

    // --- reduce 4 groups per row -> neigh into s_x[row][H_..2H_) ---
    *reinterpret_cast<float4*>(&s_red[grp * H_ + h4 * 4]) = vmax;
    __syncthreads();
    {
        const int r = t >> 7, hh = t & 127;
        float m = s_red[(r * 4 + 0) * H_ + hh];
        #pragma unroll
        for (int gg = 1; gg < 4; ++gg)
            m = fmaxf(m, s_red[(r * 4 + gg) * H_ + hh]);
        const int cnt = s_cnt[r][0] + s_cnt[r][1] + s_cnt[r][2] + s_cnt[r][3];
        if (cnt < V_) m = fmaxf(m, 0.0f);   // masked entries contribute 0
        s_x[r][H_ + hh] = m;                 // cnt==0 -> max(-inf,0)=0
    }
    __syncthreads();

    // --- epilogue: h1 = silu(x @ W_post + b_post); out = silu(skip + h1) ---
    // thread (c, half): accumulate both rows per W_post load.
    const int c    = t & 127;
    const int half = t >> 7;
    const float* __restrict__ wp = W_post + (size_t)(half * H_) * H_ + c;
    float acc0 = 0.f, acc1 = 0.f;
    #pragma unroll 8
    for (int kk = 0; kk < H_; ++kk) {
        const float w = wp[(size_t)kk * H_];
        acc0 += s_x[0][half * H_ + kk] * w;
        acc1 += s_x[1][half * H_ + kk] * w;
    }
    s_part[(half * 2 + 0) * H_ + c] = acc0;
    s_part[(half * 2 + 1) * H_ + c] = acc1;
    __syncthreads();
    {
        const int r = t >> 7, cc = t & 127;
        const float h1 = silu_f(s_part[(0 * 2 + r) * H_ + cc]
                              + s_part[(1 * 2 + r) * H_ + cc] + b_post[cc]);
        out[(bi0 + r) * H_ + cc] = silu_f(skipws[(bi0 + r) * H_ + cc] + h1);
    }
}

// ---------------------------------------------------------------------------
extern "C" void kernel_launch(void* const* d_in, const int* in_sizes, int n_in,
                              void* d_out, int out_size, void* d_ws, size_t ws_size,
                              hipStream_t stream)
{
    const float* h      = (const float*)d_in[0];
    const float* e      = (const float*)d_in[1];
    const int*   graph  = (const int*)  d_in[2];
    const float* W_pre  = (const float*)d_in[3];
    const float* b_pre  = (const float*)d_in[4];
    const float* W_post = (const float*)d_in[5];
    const float* b_post = (const float*)d_in[6];
    const float* W_skip = (const float*)d_in[7];
    const float* b_skip = (const float*)d_in[8];
    float* out = (float*)d_out;

    float* ws     = (float*)d_ws;
    float* h0ws   = ws;                    // BV*H floats = 1 MB
    float* skipws = ws + BV * H_;          // 1 MB

    k1_pre_skip<<<BV / 8, 512, 0, stream>>>(h, W_pre, b_pre, W_skip, b_skip,
                                            h0ws, skipws);
    k2_edge_max_post<<<BV / 2, 256, 0, stream>>>((const float4*)e, graph,
                                                 (const float4*)h0ws,
                                                 h0ws, skipws,
                                                 W_post, b_post, out);
}